// Round 8
// baseline (2869.594 us; speedup 1.0000x reference)
//
#include <hip/hip_runtime.h>

// Problem constants
#define B_   4
#define L_   2048
#define DIN  1024
#define DOUT 1024
#define H_   16
#define DH_  64
#define M_   (B_ * L_)   // 8192 rows

// Chunked-scan constants
#define CH_  16          // chunk length
#define NC_  (L_ / CH_)  // 128 chunks
#define TBL  544         // per-(bh,chunk) table: 256 A + 256 Aq + 16 gamma + 16 wgt

typedef __bf16 bf16x8 __attribute__((ext_vector_type(8)));
typedef float  f32x4  __attribute__((ext_vector_type(4)));

__device__ __forceinline__ float bf2f(unsigned short u) {
  union { unsigned int i; float f; } x; x.i = ((unsigned int)u) << 16; return x.f;
}
__device__ __forceinline__ unsigned short f2bf(float f) {
  union { float f; unsigned int i; } x; x.f = f;
  unsigned int r = x.i + 0x7FFFu + ((x.i >> 16) & 1u);
  return (unsigned short)(r >> 16);
}

// DPP cross-lane add (VALU latency, no DS pipe). 0xB1=quad_perm[1,0,3,2],
// 0x4E=quad_perm[2,3,0,1], 0x124=row_ror:4, 0x128=row_ror:8 -> 16-lane allreduce.
template <int CTRL>
__device__ __forceinline__ float dpp_add(float x) {
  int v = __builtin_amdgcn_update_dpp(0, __float_as_int(x), CTRL, 0xF, 0xF, false);
  return x + __int_as_float(v);
}
__device__ __forceinline__ float row16_allreduce(float x) {
  x = dpp_add<0xB1>(x);
  x = dpp_add<0x4E>(x);
  x = dpp_add<0x124>(x);
  x = dpp_add<0x128>(x);
  return x;
}

// ---------------------------------------------------------------------------
// fp32 -> (hi, lo) bf16 split: hi = bf16(x), lo = bf16(x - hi).
// ---------------------------------------------------------------------------
__global__ __launch_bounds__(256)
void cast_hilo(const float* __restrict__ in,
               unsigned short* __restrict__ hi,
               unsigned short* __restrict__ lo, int n)
{
  int i = (blockIdx.x * 256 + threadIdx.x) * 8;
  int stride = gridDim.x * 256 * 8;
  for (; i < n; i += stride) {
    float4 a = *(const float4*)(in + i);
    float4 b = *(const float4*)(in + i + 4);
    float v[8] = {a.x, a.y, a.z, a.w, b.x, b.y, b.z, b.w};
    ushort4 h0, h1, l0, l1;
    unsigned short hh[8], ll[8];
#pragma unroll
    for (int j = 0; j < 8; j++) {
      hh[j] = f2bf(v[j]);
      ll[j] = f2bf(v[j] - bf2f(hh[j]));
    }
    h0 = {hh[0], hh[1], hh[2], hh[3]}; h1 = {hh[4], hh[5], hh[6], hh[7]};
    l0 = {ll[0], ll[1], ll[2], ll[3]}; l1 = {ll[4], ll[5], ll[6], ll[7]};
    *(ushort4*)(hi + i) = h0; *(ushort4*)(hi + i + 4) = h1;
    *(ushort4*)(lo + i) = l0; *(ushort4*)(lo + i + 4) = l1;
  }
}

// ---------------------------------------------------------------------------
// GEMM core: C[M,N] = A[M,K] @ W[N,K]^T (+bias), A/W as hi/lo bf16 pairs.
// acc = hi*hi + lo*hi + hi*lo (3 MFMAs). 128x128 tile, BK=64, 4 waves 2x2.
// LDS rows padded to 72 ushort (144 B = 36 banks): consecutive rows shift by
// 4 banks, so the 16-lane fragment read (same col, rows r..r+15) is 2-way max
// (free) instead of the 16-way conflict (5.7x) of an unpadded 128 B stride.
// ---------------------------------------------------------------------------
#define LPAD 72
template <typename OutT>
__device__ __forceinline__
void gemm_hilo_core(const unsigned short* __restrict__ Ahi,
                    const unsigned short* __restrict__ Alo,
                    const unsigned short* __restrict__ Whi,
                    const unsigned short* __restrict__ Wlo,
                    OutT* __restrict__ C,
                    const float* __restrict__ bias,
                    int K, int N, int m0, int n0)
{
  __shared__ unsigned short AsH[128][LPAD];
  __shared__ unsigned short AsL[128][LPAD];
  __shared__ unsigned short BsH[128][LPAD];
  __shared__ unsigned short BsL[128][LPAD];
  const int t = threadIdx.x;
  const int w = t >> 6;
  const int lane = t & 63;
  const int wm = (w >> 1) * 64, wn = (w & 1) * 64;
  const int l15 = lane & 15, quad = lane >> 4;

  f32x4 acc[4][4] = {};

  for (int k0 = 0; k0 < K; k0 += 64) {
#pragma unroll
    for (int i = 0; i < 4; i++) {
      int c = t + 256 * i;
      int row = c >> 3;
      int col = (c & 7) * 8;
      size_t ga = (size_t)(m0 + row) * K + k0 + col;
      size_t gb = (size_t)(n0 + row) * K + k0 + col;
      *(uint4*)(&AsH[row][col]) = *(const uint4*)(Ahi + ga);
      *(uint4*)(&AsL[row][col]) = *(const uint4*)(Alo + ga);
      *(uint4*)(&BsH[row][col]) = *(const uint4*)(Whi + gb);
      *(uint4*)(&BsL[row][col]) = *(const uint4*)(Wlo + gb);
    }
    __syncthreads();
#pragma unroll
    for (int kh = 0; kh < 2; kh++) {
      bf16x8 ah[4], al[4], bh[4], bl[4];
#pragma unroll
      for (int i = 0; i < 4; i++) {
        union U { uint4 u; bf16x8 v; } u0, u1, u2, u3;
        u0.u = *(const uint4*)(&AsH[wm + i * 16 + l15][kh * 32 + quad * 8]);
        u1.u = *(const uint4*)(&AsL[wm + i * 16 + l15][kh * 32 + quad * 8]);
        u2.u = *(const uint4*)(&BsH[wn + i * 16 + l15][kh * 32 + quad * 8]);
        u3.u = *(const uint4*)(&BsL[wn + i * 16 + l15][kh * 32 + quad * 8]);
        ah[i] = u0.v; al[i] = u1.v; bh[i] = u2.v; bl[i] = u3.v;
      }
#pragma unroll
      for (int mt = 0; mt < 4; mt++)
#pragma unroll
        for (int nt = 0; nt < 4; nt++) {
          acc[mt][nt] = __builtin_amdgcn_mfma_f32_16x16x32_bf16(ah[mt], bh[nt], acc[mt][nt], 0, 0, 0);
          acc[mt][nt] = __builtin_amdgcn_mfma_f32_16x16x32_bf16(al[mt], bh[nt], acc[mt][nt], 0, 0, 0);
          acc[mt][nt] = __builtin_amdgcn_mfma_f32_16x16x32_bf16(ah[mt], bl[nt], acc[mt][nt], 0, 0, 0);
        }
    }
    __syncthreads();
  }

#pragma unroll
  for (int mt = 0; mt < 4; mt++) {
#pragma unroll
    for (int nt = 0; nt < 4; nt++) {
      int n = n0 + wn + nt * 16 + l15;
      float bv = bias ? bias[n] : 0.0f;
#pragma unroll
      for (int r = 0; r < 4; r++) {
        int m = m0 + wm + mt * 16 + quad * 4 + r;
        C[(size_t)m * N + n] = (OutT)(acc[mt][nt][r] + bv);
      }
    }
  }
}

struct WPtrs {
  const unsigned short* hi[5];
  const unsigned short* lo[5];
};

__global__ __launch_bounds__(256, 2)
void proj_gemm(const unsigned short* __restrict__ xhi,
               const unsigned short* __restrict__ xlo,
               WPtrs wp, float* __restrict__ outbase)
{
  int z = blockIdx.z;
  float* C = outbase + (size_t)z * ((size_t)M_ * DOUT);
  gemm_hilo_core<float>(xhi, xlo, wp.hi[z], wp.lo[z], C, nullptr,
                        DIN, DOUT, blockIdx.x * 128, blockIdx.y * 128);
}

__global__ __launch_bounds__(256, 2)
void final_gemm(const unsigned short* __restrict__ chi,
                const unsigned short* __restrict__ clo,
                const unsigned short* __restrict__ whi,
                const unsigned short* __restrict__ wlo,
                float* __restrict__ out, const float* __restrict__ bias)
{
  gemm_hilo_core<float>(chi, clo, whi, wlo, out, bias,
                        DOUT, DOUT, blockIdx.x * 128, blockIdx.y * 128);
}

// ---------------------------------------------------------------------------
// alpha[r,h] = exp(-exp(A_log[h]) * softplus(x[r]·Wa[h] + dt_bias[h]))
// ---------------------------------------------------------------------------
__global__ __launch_bounds__(256)
void alpha_kernel(const float* __restrict__ x,
                  const float* __restrict__ Wa,
                  const float* __restrict__ dtb,
                  const float* __restrict__ Alg,
                  float* __restrict__ alpha)
{
  __shared__ float WaS[16 * 1024];
  const int t = threadIdx.x;
#pragma unroll
  for (int i = 0; i < 16; i++) {
    int idx = (t + 256 * i) * 4;
    *(float4*)(&WaS[idx]) = *(const float4*)(Wa + idx);
  }
  __syncthreads();
  const int w = t >> 6, lane = t & 63;
  for (int r = blockIdx.x * 4 + w; r < M_; r += gridDim.x * 4) {
    const float* xr = x + (size_t)r * DIN + lane * 16;
    float xv[16];
#pragma unroll
    for (int j = 0; j < 4; j++) {
      float4 a = *(const float4*)(xr + j * 4);
      xv[j * 4 + 0] = a.x; xv[j * 4 + 1] = a.y; xv[j * 4 + 2] = a.z; xv[j * 4 + 3] = a.w;
    }
#pragma unroll 1
    for (int h = 0; h < 16; h++) {
      const float* wr = &WaS[h * 1024 + lane * 16];
      float p = 0.f;
#pragma unroll
      for (int j = 0; j < 4; j++) {
        float4 b = *(const float4*)(wr + j * 4);
        p += xv[j * 4 + 0] * b.x + xv[j * 4 + 1] * b.y +
             xv[j * 4 + 2] * b.z + xv[j * 4 + 3] * b.w;
      }
#pragma unroll
      for (int o = 32; o >= 1; o >>= 1) p += __shfl_xor(p, o, 64);
      if (lane == h) {
        float z = p + dtb[h];
        float sp = (z > 20.f) ? z : log1pf(expf(z));
        alpha[(size_t)r * 16 + h] = expf(-expf(Alg[h]) * sp);
      }
    }
  }
}

// ---------------------------------------------------------------------------
// In-place fp32: q <- q/||q||/8, k <- k/||k||, beta <- sigmoid(beta_raw).
// ---------------------------------------------------------------------------
__global__ __launch_bounds__(256)
void qkb_kernel(float* __restrict__ q,
                float* __restrict__ k,
                float* __restrict__ bta)
{
  const int t = threadIdx.x, w = t >> 6, lane = t & 63;
  const int NP = M_ * H_;
  for (int p = blockIdx.x * 4 + w; p < NP; p += gridDim.x * 4) {
    size_t off = (size_t)p * 64 + lane;
    float qv = q[off];
    float kv = k[off];
    float bv = bta[off];
    float qs = qv * qv, ks = kv * kv;
#pragma unroll
    for (int o = 32; o >= 1; o >>= 1) {
      qs += __shfl_xor(qs, o, 64);
      ks += __shfl_xor(ks, o, 64);
    }
    q[off] = qv * rsqrtf(qs) * 0.125f;
    k[off] = kv * rsqrtf(ks);
    bta[off] = 1.0f / (1.0f + expf(-bv));
  }
}

// ---------------------------------------------------------------------------
// Chunk-table precompute (parallel over all 64*128 (bh,chunk) pairs, x4 waves
// per chunk for t-quads). Per (bh,chunk): with gamma_t = prod_{j<=t} a_j and
// R[t][s] = prod_{s<j<=t} a_j (built by products, never division):
//   A [t][s] = R[t][s]*(k_t.k_s)  (s< t, else 0)
//   Aq[t][s] = R[t][s]*(q_t.k_s)  (s<=t, else 0)
//   gam[t]   = a_0 * R[t][0]
//   wgt[s]   = R[C-1][s]
// Runs after qkb (q,k normalized). 16-lane groups: lane i holds d=4i..4i+3;
// group sg of wave tq computes row t = tq*4+sg.
// ---------------------------------------------------------------------------
__global__ __launch_bounds__(256)
void chunk_tab_kernel(const float* __restrict__ q,
                      const float* __restrict__ k,
                      const float* __restrict__ alpha,
                      float* __restrict__ tab)
{
  const int bh = blockIdx.x >> 7;          // 0..63
  const int c  = blockIdx.x & (NC_ - 1);   // 0..127
  const int b  = bh >> 4, h = bh & 15;
  const int tq = threadIdx.x >> 6;
  const int lane = threadIdx.x & 63;
  const int sg = lane >> 4;
  const int i  = lane & 15;
  const int t  = tq * 4 + sg;
  const int T0 = c * CH_;

  const size_t rowstride = 1024;
  const size_t bhbase = (size_t)b * L_ * rowstride + (size_t)h * 64;
  const float* kp = k + bhbase + 4 * i;
  const float* qp = q + bhbase + 4 * i;
  const float* ap = alpha + ((size_t)b * L_ + T0) * 16 + h;

  float a[CH_];
#pragma unroll
  for (int j = 0; j < CH_; j++) a[j] = ap[(size_t)j * 16];

  float R[CH_];
  R[CH_ - 1] = 1.0f;                       // s=15 >= t for all t
#pragma unroll
  for (int s = CH_ - 2; s >= 0; s--)
    R[s] = (s >= t) ? 1.0f : a[s + 1] * R[s + 1];
  float gam = a[0] * R[0];

  float4 kt = *(const float4*)(kp + (size_t)(T0 + t) * rowstride);
  float4 qt = *(const float4*)(qp + (size_t)(T0 + t) * rowstride);

  float Av = 0.f, Aqv = 0.f, wv = 0.f;
#pragma unroll
  for (int s = 0; s < CH_; s++) {
    float4 ks = *(const float4*)(kp + (size_t)(T0 + s) * rowstride);
    float pk = kt.x * ks.x + kt.y * ks.y + kt.z * ks.z + kt.w * ks.w;
    float pq = qt.x * ks.x + qt.y * ks.y + qt.z * ks.z + qt.w * ks.w;
    pk = row16_allreduce(pk);
    pq = row16_allreduce(pq);
    float Ae  = (s < t)  ? R[s] * pk : 0.f;
    float Aqe = (s <= t) ? R[s] * pq : 0.f;
    if (i == s) { Av = Ae; Aqv = Aqe; wv = R[s]; }
  }

  float* tb = tab + ((size_t)bh * NC_ + c) * TBL;
  tb[t * 16 + i] = Av;
  tb[256 + t * 16 + i] = Aqv;
  if (i == 0) tb[512 + t] = gam;
  if (t == CH_ - 1) tb[528 + i] = wv;
}

// ---------------------------------------------------------------------------
// Scan v11: chunked delta rule, C=16, register-safe codegen.
// R7 post-mortem: VGPR=48 + VALUBusy=8% proved the per-thread arrays were
// demoted to scratch; the trigger was the by-reference float4 helper (taking
// addresses of array elements) + 190-reg peak pressure from kc[16]/gm/wg.
// Fixes: (a) no references — explicit .x/.y/.z/.w with static guards;
// (b) kc[] removed, k rows reloaded in phase 4 (L1-hot, shared by the
// block's 4 waves); (c) gamma/wgt read as uniform scalars at use sites.
// Remaining arrays: dkq/dqg/bfac/dl = 64 floats, all statically indexed.
//   phase 1: 32 INDEPENDENT dots vs fixed S0 (allreduce latencies overlap)
//   phase 2: forward substitution — dependent chain = 2 VALU ops/step
//   phase 3: triangular y accumulation (off-chain)
//   phase 4: one state update per chunk
// blockIdx = part*64 + bh keeps the 4 blocks of one (b,h) on one XCD.
// ---------------------------------------------------------------------------
__global__ __launch_bounds__(256, 1)
void scan_kernel(const float* __restrict__ q,
                 const float* __restrict__ k,
                 const float* __restrict__ v,
                 const float* __restrict__ bta,
                 const float* __restrict__ tab,
                 float* __restrict__ ys)
{
  const int bl = blockIdx.x;
  const int bh = bl & 63;
  const int part = bl >> 6;                  // 0..3
  const int b = bh >> 4, h = bh & 15;
  const int w = threadIdx.x >> 6;
  const int lane = threadIdx.x & 63;
  const int g = part * 4 + w;                // e-group 0..15
  const int sg = lane >> 4;
  const int i = lane & 15;
  const int e = g * 4 + sg;

  const size_t rowstride = 1024;
  const size_t bhbase = (size_t)b * L_ * rowstride + (size_t)h * 64;
  const float* kp = k + bhbase + 4 * i;
  const float* qp = q + bhbase + 4 * i;
  const float* vp = v + bhbase + e;
  const float* bp = bta + bhbase + e;
  const float* tb = tab + (size_t)bh * NC_ * TBL;

  float Sx = 0.f, Sy = 0.f, Sz = 0.f, Sw = 0.f;

#pragma unroll 1
  for (int c = 0; c < NC_; c++, tb += TBL) {
    const int T0 = c * CH_;

    // ---- phase 1: dots against S0 (independent; latencies overlap) ----
    float dkq[CH_];   // v_t - gamma_t*(k_t.S0)
    float dqg[CH_];   // gamma_t*(q_t.S0)
    float bfac[CH_];  // beta_t (per e)
#pragma unroll
    for (int t = 0; t < CH_; t++) {
      size_t o = (size_t)(T0 + t) * rowstride;
      float4 kt = *(const float4*)(kp + o);
      float4 qt = *(const float4*)(qp + o);
      float pk = kt.x * Sx + kt.y * Sy + kt.z * Sz + kt.w * Sw;
      float pq = qt.x * Sx + qt.y * Sy + qt.z * Sz + qt.w * Sw;
      pk = row16_allreduce(pk);
      pq = row16_allreduce(pq);
      float gt = tb[512 + t];
      float vc = vp[o];
      bfac[t] = bp[o];
      dkq[t] = vc - gt * pk;
      dqg[t] = gt * pq;
    }

    // ---- phase 2: forward substitution (chain = 2 ops/step) ----
    float dl[CH_];
#pragma unroll
    for (int t = 0; t < CH_; t++) {
      float acc = dkq[t];
#pragma unroll
      for (int s4 = 0; s4 * 4 < t; s4++) {
        float4 Ar = *(const float4*)(tb + t * 16 + 4 * s4);
        if (s4 * 4 + 0 < t) acc -= Ar.x * dl[s4 * 4 + 0];
        if (s4 * 4 + 1 < t) acc -= Ar.y * dl[s4 * 4 + 1];
        if (s4 * 4 + 2 < t) acc -= Ar.z * dl[s4 * 4 + 2];
        if (s4 * 4 + 3 < t) acc -= Ar.w * dl[s4 * 4 + 3];
      }
      dl[t] = bfac[t] * acc;
    }

    // ---- phase 3: y = gamma*(q.S0) + tril(Aq) @ delta ----
    float Y = 0.f;
#pragma unroll
    for (int t = 0; t < CH_; t++) {
      float yv = dqg[t];
#pragma unroll
      for (int s4 = 0; s4 * 4 <= t; s4++) {
        float4 Ar = *(const float4*)(tb + 256 + t * 16 + 4 * s4);
        if (s4 * 4 + 0 <= t) yv = fmaf(Ar.x, dl[s4 * 4 + 0], yv);
        if (s4 * 4 + 1 <= t) yv = fmaf(Ar.y, dl[s4 * 4 + 1], yv);
        if (s4 * 4 + 2 <= t) yv = fmaf(Ar.z, dl[s4 * 4 + 2], yv);
        if (s4 * 4 + 3 <= t) yv = fmaf(Ar.w, dl[s4 * 4 + 3], yv);
      }
      if (i == t) Y = yv;
    }
    ys[bhbase + (size_t)(T0 + i) * rowstride + e] = Y;

    // ---- phase 4: S = gam[15]*S0 + sum_s wgt[s]*delta_s*k_s (k reloaded) ----
    float g15 = tb[512 + 15];
    Sx *= g15; Sy *= g15; Sz *= g15; Sw *= g15;
#pragma unroll
    for (int s = 0; s < CH_; s++) {
      float4 ks4 = *(const float4*)(kp + (size_t)(T0 + s) * rowstride);
      float cs = tb[528 + s] * dl[s];
      Sx = fmaf(cs, ks4.x, Sx);
      Sy = fmaf(cs, ks4.y, Sy);
      Sz = fmaf(cs, ks4.z, Sz);
      Sw = fmaf(cs, ks4.w, Sw);
    }
  }
}

// ---------------------------------------------------------------------------
// ctx = rmsnorm(ys, norm_w) * silu(gate), written directly as hi/lo bf16
// (fuses the ctx cast_hilo pass: saves one 67 MB kernel).
// ---------------------------------------------------------------------------
__global__ __launch_bounds__(256)
void out_gate_kernel(const float* __restrict__ ys,
                     const float* __restrict__ g,
                     const float* __restrict__ norm_w,
                     unsigned short* __restrict__ chi,
                     unsigned short* __restrict__ clo)
{
  const int t = threadIdx.x, w = t >> 6, lane = t & 63;
  const int NP = M_ * H_;
  float nw = norm_w[lane];
  for (int p = blockIdx.x * 4 + w; p < NP; p += gridDim.x * 4) {
    size_t off = (size_t)p * 64 + lane;
    float y = ys[off];
    float gv = g[off];
    float s = y * y;
#pragma unroll
    for (int o = 32; o >= 1; o >>= 1) s += __shfl_xor(s, o, 64);
    float rs = rsqrtf(s * (1.0f / 64.0f) + 1e-6f);
    float silu = gv / (1.0f + expf(-gv));
    float c = y * rs * nw * silu;
    unsigned short hh = f2bf(c);
    chi[off] = hh;
    clo[off] = f2bf(c - bf2f(hh));
  }
}

// ---------------------------------------------------------------------------
extern "C" void kernel_launch(void* const* d_in, const int* in_sizes, int n_in,
                              void* d_out, int out_size, void* d_ws, size_t ws_size,
                              hipStream_t stream)
{
  const float* x   = (const float*)d_in[0];
  const float* Wq  = (const float*)d_in[1];
  const float* Wk  = (const float*)d_in[2];
  const float* Wv  = (const float*)d_in[3];
  const float* Wg  = (const float*)d_in[4];
  const float* Wb  = (const float*)d_in[5];
  const float* Wa  = (const float*)d_in[6];
  const float* dtb = (const float*)d_in[7];
  const float* Alg = (const float*)d_in[8];
  const float* nw  = (const float*)d_in[9];
  const float* Wo  = (const float*)d_in[10];
  const float* bo  = (const float*)d_in[11];

  const size_t TSZ = (size_t)M_ * DOUT;   // 8,388,608
  const size_t WSZ = (size_t)DOUT * DIN;  // 1,048,576

  float* q    = (float*)d_ws;             // projections q,k,v,g,bta contiguous
  float* k    = q + TSZ;
  float* v    = k + TSZ;
  float* g    = v + TSZ;
  float* bta  = g + TSZ;
  float* ys   = bta + TSZ;
  float* alph = ys + TSZ;                 // M_*H_ floats
  unsigned short* whl = (unsigned short*)(alph + (size_t)M_ * H_);
  unsigned short* whi[6], *wlo[6];
  for (int j = 0; j < 6; j++) { whi[j] = whl + (size_t)(2 * j) * WSZ; wlo[j] = whl + (size_t)(2 * j + 1) * WSZ; }
  // x hi/lo aliased into ys region (dead until scan)
  unsigned short* xhi = (unsigned short*)ys;
  unsigned short* xlo = xhi + TSZ;
  // ctx hi/lo aliased into q region (q dead after scan)
  unsigned short* chi = (unsigned short*)q;
  unsigned short* clo = chi + TSZ;
  float* outp = (float*)d_out;
  // chunk tables aliased into d_out (17.8 MB < 33.5 MB; d_out written only by
  // final_gemm, which runs after the scan consumed the tables — R1-validated).
  float* tabw = (float*)d_out;

  cast_hilo<<<2048, 256, 0, stream>>>(x, xhi, xlo, (int)TSZ);
  cast_hilo<<<512, 256, 0, stream>>>(Wq, whi[0], wlo[0], (int)WSZ);
  cast_hilo<<<512, 256, 0, stream>>>(Wk, whi[1], wlo[1], (int)WSZ);
  cast_hilo<<<512, 256, 0, stream>>>(Wv, whi[2], wlo[2], (int)WSZ);
  cast_hilo<<<512, 256, 0, stream>>>(Wg, whi[3], wlo[3], (int)WSZ);
  cast_hilo<<<512, 256, 0, stream>>>(Wb, whi[4], wlo[4], (int)WSZ);
  cast_hilo<<<512, 256, 0, stream>>>(Wo, whi[5], wlo[5], (int)WSZ);

  WPtrs wp;
  for (int j = 0; j < 5; j++) { wp.hi[j] = whi[j]; wp.lo[j] = wlo[j]; }
  dim3 gp(M_ / 128, DOUT / 128, 5);
  proj_gemm<<<gp, 256, 0, stream>>>(xhi, xlo, wp, q);

  alpha_kernel<<<128, 256, 0, stream>>>(x, Wa, dtb, Alg, alph);
  qkb_kernel<<<1024, 256, 0, stream>>>(q, k, bta);
  chunk_tab_kernel<<<64 * NC_, 256, 0, stream>>>(q, k, alph, tabw);
  scan_kernel<<<256, 256, 0, stream>>>(q, k, v, bta, tabw, ys);
  out_gate_kernel<<<1024, 256, 0, stream>>>(ys, g, nw, chi, clo);

  dim3 gf(M_ / 128, DOUT / 128);
  final_gemm<<<gf, 256, 0, stream>>>(chi, clo, whi[5], wlo[5], outp, bo);
}

// Round 9
// 1895.025 us; speedup vs baseline: 1.5143x; 1.5143x over previous
//
#include <hip/hip_runtime.h>

// Problem constants
#define B_   4
#define L_   2048
#define DIN  1024
#define DOUT 1024
#define H_   16
#define DH_  64
#define M_   (B_ * L_)   // 8192 rows

// Chunked-scan constants
#define CH_  16          // chunk length
#define NC_  (L_ / CH_)  // 128 chunks
#define TBL  544         // per-(bh,chunk) table: 256 A + 256 Aq + 16 gamma + 16 wgt

typedef __bf16 bf16x8 __attribute__((ext_vector_type(8)));
typedef float  f32x4  __attribute__((ext_vector_type(4)));

__device__ __forceinline__ float bf2f(unsigned short u) {
  union { unsigned int i; float f; } x; x.i = ((unsigned int)u) << 16; return x.f;
}
__device__ __forceinline__ unsigned short f2bf(float f) {
  union { float f; unsigned int i; } x; x.f = f;
  unsigned int r = x.i + 0x7FFFu + ((x.i >> 16) & 1u);
  return (unsigned short)(r >> 16);
}

// DPP cross-lane add (VALU latency, no DS pipe). 0xB1=quad_perm[1,0,3,2],
// 0x4E=quad_perm[2,3,0,1], 0x124=row_ror:4, 0x128=row_ror:8 -> 16-lane allreduce.
template <int CTRL>
__device__ __forceinline__ float dpp_add(float x) {
  int v = __builtin_amdgcn_update_dpp(0, __float_as_int(x), CTRL, 0xF, 0xF, false);
  return x + __int_as_float(v);
}
__device__ __forceinline__ float row16_allreduce(float x) {
  x = dpp_add<0xB1>(x);
  x = dpp_add<0x4E>(x);
  x = dpp_add<0x124>(x);
  x = dpp_add<0x128>(x);
  return x;
}

// ---------------------------------------------------------------------------
// fp32 -> (hi, lo) bf16 split: hi = bf16(x), lo = bf16(x - hi).
// ---------------------------------------------------------------------------
__global__ __launch_bounds__(256)
void cast_hilo(const float* __restrict__ in,
               unsigned short* __restrict__ hi,
               unsigned short* __restrict__ lo, int n)
{
  int i = (blockIdx.x * 256 + threadIdx.x) * 8;
  int stride = gridDim.x * 256 * 8;
  for (; i < n; i += stride) {
    float4 a = *(const float4*)(in + i);
    float4 b = *(const float4*)(in + i + 4);
    float v[8] = {a.x, a.y, a.z, a.w, b.x, b.y, b.z, b.w};
    ushort4 h0, h1, l0, l1;
    unsigned short hh[8], ll[8];
#pragma unroll
    for (int j = 0; j < 8; j++) {
      hh[j] = f2bf(v[j]);
      ll[j] = f2bf(v[j] - bf2f(hh[j]));
    }
    h0 = {hh[0], hh[1], hh[2], hh[3]}; h1 = {hh[4], hh[5], hh[6], hh[7]};
    l0 = {ll[0], ll[1], ll[2], ll[3]}; l1 = {ll[4], ll[5], ll[6], ll[7]};
    *(ushort4*)(hi + i) = h0; *(ushort4*)(hi + i + 4) = h1;
    *(ushort4*)(lo + i) = l0; *(ushort4*)(lo + i + 4) = l1;
  }
}

// ---------------------------------------------------------------------------
// GEMM core: C[M,N] = A[M,K] @ W[N,K]^T (+bias), A/W as hi/lo bf16 pairs.
// acc = hi*hi + lo*hi + hi*lo (3 MFMAs). 128x128 tile, BK=64, 4 waves 2x2.
// LDS rows padded to 72 ushort (144 B = 36 banks): consecutive rows shift by
// 4 banks, so the 16-lane fragment read (same col, rows r..r+15) is 2-way max
// (free) instead of the 16-way conflict (5.7x) of an unpadded 128 B stride.
// ---------------------------------------------------------------------------
#define LPAD 72
template <typename OutT>
__device__ __forceinline__
void gemm_hilo_core(const unsigned short* __restrict__ Ahi,
                    const unsigned short* __restrict__ Alo,
                    const unsigned short* __restrict__ Whi,
                    const unsigned short* __restrict__ Wlo,
                    OutT* __restrict__ C,
                    const float* __restrict__ bias,
                    int K, int N, int m0, int n0)
{
  __shared__ unsigned short AsH[128][LPAD];
  __shared__ unsigned short AsL[128][LPAD];
  __shared__ unsigned short BsH[128][LPAD];
  __shared__ unsigned short BsL[128][LPAD];
  const int t = threadIdx.x;
  const int w = t >> 6;
  const int lane = t & 63;
  const int wm = (w >> 1) * 64, wn = (w & 1) * 64;
  const int l15 = lane & 15, quad = lane >> 4;

  f32x4 acc[4][4] = {};

  for (int k0 = 0; k0 < K; k0 += 64) {
#pragma unroll
    for (int i = 0; i < 4; i++) {
      int c = t + 256 * i;
      int row = c >> 3;
      int col = (c & 7) * 8;
      size_t ga = (size_t)(m0 + row) * K + k0 + col;
      size_t gb = (size_t)(n0 + row) * K + k0 + col;
      *(uint4*)(&AsH[row][col]) = *(const uint4*)(Ahi + ga);
      *(uint4*)(&AsL[row][col]) = *(const uint4*)(Alo + ga);
      *(uint4*)(&BsH[row][col]) = *(const uint4*)(Whi + gb);
      *(uint4*)(&BsL[row][col]) = *(const uint4*)(Wlo + gb);
    }
    __syncthreads();
#pragma unroll
    for (int kh = 0; kh < 2; kh++) {
      bf16x8 ah[4], al[4], bh[4], bl[4];
#pragma unroll
      for (int i = 0; i < 4; i++) {
        union U { uint4 u; bf16x8 v; } u0, u1, u2, u3;
        u0.u = *(const uint4*)(&AsH[wm + i * 16 + l15][kh * 32 + quad * 8]);
        u1.u = *(const uint4*)(&AsL[wm + i * 16 + l15][kh * 32 + quad * 8]);
        u2.u = *(const uint4*)(&BsH[wn + i * 16 + l15][kh * 32 + quad * 8]);
        u3.u = *(const uint4*)(&BsL[wn + i * 16 + l15][kh * 32 + quad * 8]);
        ah[i] = u0.v; al[i] = u1.v; bh[i] = u2.v; bl[i] = u3.v;
      }
#pragma unroll
      for (int mt = 0; mt < 4; mt++)
#pragma unroll
        for (int nt = 0; nt < 4; nt++) {
          acc[mt][nt] = __builtin_amdgcn_mfma_f32_16x16x32_bf16(ah[mt], bh[nt], acc[mt][nt], 0, 0, 0);
          acc[mt][nt] = __builtin_amdgcn_mfma_f32_16x16x32_bf16(al[mt], bh[nt], acc[mt][nt], 0, 0, 0);
          acc[mt][nt] = __builtin_amdgcn_mfma_f32_16x16x32_bf16(ah[mt], bl[nt], acc[mt][nt], 0, 0, 0);
        }
    }
    __syncthreads();
  }

#pragma unroll
  for (int mt = 0; mt < 4; mt++) {
#pragma unroll
    for (int nt = 0; nt < 4; nt++) {
      int n = n0 + wn + nt * 16 + l15;
      float bv = bias ? bias[n] : 0.0f;
#pragma unroll
      for (int r = 0; r < 4; r++) {
        int m = m0 + wm + mt * 16 + quad * 4 + r;
        C[(size_t)m * N + n] = (OutT)(acc[mt][nt][r] + bv);
      }
    }
  }
}

struct WPtrs {
  const unsigned short* hi[5];
  const unsigned short* lo[5];
};

__global__ __launch_bounds__(256, 2)
void proj_gemm(const unsigned short* __restrict__ xhi,
               const unsigned short* __restrict__ xlo,
               WPtrs wp, float* __restrict__ outbase)
{
  int z = blockIdx.z;
  float* C = outbase + (size_t)z * ((size_t)M_ * DOUT);
  gemm_hilo_core<float>(xhi, xlo, wp.hi[z], wp.lo[z], C, nullptr,
                        DIN, DOUT, blockIdx.x * 128, blockIdx.y * 128);
}

__global__ __launch_bounds__(256, 2)
void final_gemm(const unsigned short* __restrict__ chi,
                const unsigned short* __restrict__ clo,
                const unsigned short* __restrict__ whi,
                const unsigned short* __restrict__ wlo,
                float* __restrict__ out, const float* __restrict__ bias)
{
  gemm_hilo_core<float>(chi, clo, whi, wlo, out, bias,
                        DOUT, DOUT, blockIdx.x * 128, blockIdx.y * 128);
}

// ---------------------------------------------------------------------------
// alpha[r,h] = exp(-exp(A_log[h]) * softplus(x[r]·Wa[h] + dt_bias[h]))
// ---------------------------------------------------------------------------
__global__ __launch_bounds__(256)
void alpha_kernel(const float* __restrict__ x,
                  const float* __restrict__ Wa,
                  const float* __restrict__ dtb,
                  const float* __restrict__ Alg,
                  float* __restrict__ alpha)
{
  __shared__ float WaS[16 * 1024];
  const int t = threadIdx.x;
#pragma unroll
  for (int i = 0; i < 16; i++) {
    int idx = (t + 256 * i) * 4;
    *(float4*)(&WaS[idx]) = *(const float4*)(Wa + idx);
  }
  __syncthreads();
  const int w = t >> 6, lane = t & 63;
  for (int r = blockIdx.x * 4 + w; r < M_; r += gridDim.x * 4) {
    const float* xr = x + (size_t)r * DIN + lane * 16;
    float xv[16];
#pragma unroll
    for (int j = 0; j < 4; j++) {
      float4 a = *(const float4*)(xr + j * 4);
      xv[j * 4 + 0] = a.x; xv[j * 4 + 1] = a.y; xv[j * 4 + 2] = a.z; xv[j * 4 + 3] = a.w;
    }
#pragma unroll 1
    for (int h = 0; h < 16; h++) {
      const float* wr = &WaS[h * 1024 + lane * 16];
      float p = 0.f;
#pragma unroll
      for (int j = 0; j < 4; j++) {
        float4 b = *(const float4*)(wr + j * 4);
        p += xv[j * 4 + 0] * b.x + xv[j * 4 + 1] * b.y +
             xv[j * 4 + 2] * b.z + xv[j * 4 + 3] * b.w;
      }
#pragma unroll
      for (int o = 32; o >= 1; o >>= 1) p += __shfl_xor(p, o, 64);
      if (lane == h) {
        float z = p + dtb[h];
        float sp = (z > 20.f) ? z : log1pf(expf(z));
        alpha[(size_t)r * 16 + h] = expf(-expf(Alg[h]) * sp);
      }
    }
  }
}

// ---------------------------------------------------------------------------
// In-place fp32: q <- q/||q||/8, k <- k/||k||, beta <- sigmoid(beta_raw).
// ---------------------------------------------------------------------------
__global__ __launch_bounds__(256)
void qkb_kernel(float* __restrict__ q,
                float* __restrict__ k,
                float* __restrict__ bta)
{
  const int t = threadIdx.x, w = t >> 6, lane = t & 63;
  const int NP = M_ * H_;
  for (int p = blockIdx.x * 4 + w; p < NP; p += gridDim.x * 4) {
    size_t off = (size_t)p * 64 + lane;
    float qv = q[off];
    float kv = k[off];
    float bv = bta[off];
    float qs = qv * qv, ks = kv * kv;
#pragma unroll
    for (int o = 32; o >= 1; o >>= 1) {
      qs += __shfl_xor(qs, o, 64);
      ks += __shfl_xor(ks, o, 64);
    }
    q[off] = qv * rsqrtf(qs) * 0.125f;
    k[off] = kv * rsqrtf(ks);
    bta[off] = 1.0f / (1.0f + expf(-bv));
  }
}

// ---------------------------------------------------------------------------
// Chunk-table precompute (parallel over all 64*128 (bh,chunk) pairs, x4 waves
// per chunk for t-quads). Per (bh,chunk): with gamma_t = prod_{j<=t} a_j and
// R[t][s] = prod_{s<j<=t} a_j (built by products, never division):
//   A [t][s] = R[t][s]*(k_t.k_s)  (s< t, else 0)
//   Aq[t][s] = R[t][s]*(q_t.k_s)  (s<=t, else 0)
//   gam[t]   = a_0 * R[t][0]
//   wgt[s]   = R[C-1][s]
// Runs after qkb (q,k normalized). 16-lane groups: lane i holds d=4i..4i+3;
// group sg of wave tq computes row t = tq*4+sg.
// ---------------------------------------------------------------------------
__global__ __launch_bounds__(256)
void chunk_tab_kernel(const float* __restrict__ q,
                      const float* __restrict__ k,
                      const float* __restrict__ alpha,
                      float* __restrict__ tab)
{
  const int bh = blockIdx.x >> 7;          // 0..63
  const int c  = blockIdx.x & (NC_ - 1);   // 0..127
  const int b  = bh >> 4, h = bh & 15;
  const int tq = threadIdx.x >> 6;
  const int lane = threadIdx.x & 63;
  const int sg = lane >> 4;
  const int i  = lane & 15;
  const int t  = tq * 4 + sg;
  const int T0 = c * CH_;

  const size_t rowstride = 1024;
  const size_t bhbase = (size_t)b * L_ * rowstride + (size_t)h * 64;
  const float* kp = k + bhbase + 4 * i;
  const float* qp = q + bhbase + 4 * i;
  const float* ap = alpha + ((size_t)b * L_ + T0) * 16 + h;

  float a[CH_];
#pragma unroll
  for (int j = 0; j < CH_; j++) a[j] = ap[(size_t)j * 16];

  float R[CH_];
  R[CH_ - 1] = 1.0f;                       // s=15 >= t for all t
#pragma unroll
  for (int s = CH_ - 2; s >= 0; s--)
    R[s] = (s >= t) ? 1.0f : a[s + 1] * R[s + 1];
  float gam = a[0] * R[0];

  float4 kt = *(const float4*)(kp + (size_t)(T0 + t) * rowstride);
  float4 qt = *(const float4*)(qp + (size_t)(T0 + t) * rowstride);

  float Av = 0.f, Aqv = 0.f, wv = 0.f;
#pragma unroll
  for (int s = 0; s < CH_; s++) {
    float4 ks = *(const float4*)(kp + (size_t)(T0 + s) * rowstride);
    float pk = kt.x * ks.x + kt.y * ks.y + kt.z * ks.z + kt.w * ks.w;
    float pq = qt.x * ks.x + qt.y * ks.y + qt.z * ks.z + qt.w * ks.w;
    pk = row16_allreduce(pk);
    pq = row16_allreduce(pq);
    float Ae  = (s < t)  ? R[s] * pk : 0.f;
    float Aqe = (s <= t) ? R[s] * pq : 0.f;
    if (i == s) { Av = Ae; Aqv = Aqe; wv = R[s]; }
  }

  float* tb = tab + ((size_t)bh * NC_ + c) * TBL;
  tb[t * 16 + i] = Av;
  tb[256 + t * 16 + i] = Aqv;
  if (i == 0) tb[512 + t] = gam;
  if (t == CH_ - 1) tb[528 + i] = wv;
}

// ---------------------------------------------------------------------------
// Scan v12: chunked delta rule, C=16, FULLY SCALARIZED (no C arrays at all).
// R7/R8 post-mortem: C arrays were demoted to scratch (VGPR 48/64, VALUBusy
// 8%) because SROA runs before unrolling and sees dynamic indices. Named
// scalars are individual SSA values — cannot be demoted. Table reads tb[..]
// are block-uniform -> s_load/SGPR operands (SGPR=112 in R8), costing no
// VGPRs. Forward-substitution terms are ordered so each dl_t expression ends
// with its dl_{t-1} term: serial chain ~2 ops/step, earlier terms fill the
// shadow. blockIdx = part*64 + bh keeps the 4 blocks of one (b,h) on one XCD.
// ---------------------------------------------------------------------------
__global__ __launch_bounds__(256, 1)
void scan_kernel(const float* __restrict__ q,
                 const float* __restrict__ k,
                 const float* __restrict__ v,
                 const float* __restrict__ bta,
                 const float* __restrict__ tab,
                 float* __restrict__ ys)
{
  const int bl = blockIdx.x;
  const int bh = bl & 63;
  const int part = bl >> 6;                  // 0..3
  const int b = bh >> 4, h = bh & 15;
  const int w = threadIdx.x >> 6;
  const int lane = threadIdx.x & 63;
  const int g = part * 4 + w;                // e-group 0..15
  const int sg = lane >> 4;
  const int i = lane & 15;
  const int e = g * 4 + sg;

  const size_t rowstride = 1024;
  const size_t bhbase = (size_t)b * L_ * rowstride + (size_t)h * 64;
  const float* kp = k + bhbase + 4 * i;
  const float* qp = q + bhbase + 4 * i;
  const float* vp = v + bhbase + e;
  const float* bp = bta + bhbase + e;
  const float* tb = tab + (size_t)bh * NC_ * TBL;

  float Sx = 0.f, Sy = 0.f, Sz = 0.f, Sw = 0.f;

#define AT(T,S) tb[(T) * 16 + (S)]
#define AQ(T,S) tb[256 + (T) * 16 + (S)]

#pragma unroll 1
  for (int c = 0; c < NC_; c++, tb += TBL) {
    const int T0 = c * CH_;

    // ---- phase 1: dots against S0 (independent; latencies overlap) ----
    float dkq0, dkq1, dkq2, dkq3, dkq4, dkq5, dkq6, dkq7,
          dkq8, dkq9, dkq10, dkq11, dkq12, dkq13, dkq14, dkq15;
    float dqg0, dqg1, dqg2, dqg3, dqg4, dqg5, dqg6, dqg7,
          dqg8, dqg9, dqg10, dqg11, dqg12, dqg13, dqg14, dqg15;
    float bf0, bf1, bf2, bf3, bf4, bf5, bf6, bf7,
          bf8, bf9, bf10, bf11, bf12, bf13, bf14, bf15;

#define P1(T)                                                              \
    {                                                                      \
      size_t o = (size_t)(T0 + T) * rowstride;                             \
      float4 kt = *(const float4*)(kp + o);                                \
      float4 qt = *(const float4*)(qp + o);                                \
      float pk = kt.x * Sx + kt.y * Sy + kt.z * Sz + kt.w * Sw;            \
      float pq = qt.x * Sx + qt.y * Sy + qt.z * Sz + qt.w * Sw;            \
      pk = row16_allreduce(pk);                                            \
      pq = row16_allreduce(pq);                                            \
      float gt = tb[512 + T];                                              \
      dkq##T = vp[o] - gt * pk;                                            \
      dqg##T = gt * pq;                                                    \
      bf##T = bp[o];                                                       \
    }
    P1(0) P1(1) P1(2) P1(3) P1(4) P1(5) P1(6) P1(7)
    P1(8) P1(9) P1(10) P1(11) P1(12) P1(13) P1(14) P1(15)
#undef P1

    // ---- phase 2: forward substitution (terms ordered: dl_{t-1} last) ----
    float dl0  = bf0 * dkq0;
    float dl1  = bf1 * (dkq1 - AT(1,0)*dl0);
    float dl2  = bf2 * (dkq2 - AT(2,0)*dl0 - AT(2,1)*dl1);
    float dl3  = bf3 * (dkq3 - AT(3,0)*dl0 - AT(3,1)*dl1 - AT(3,2)*dl2);
    float dl4  = bf4 * (dkq4 - AT(4,0)*dl0 - AT(4,1)*dl1 - AT(4,2)*dl2 - AT(4,3)*dl3);
    float dl5  = bf5 * (dkq5 - AT(5,0)*dl0 - AT(5,1)*dl1 - AT(5,2)*dl2 - AT(5,3)*dl3 - AT(5,4)*dl4);
    float dl6  = bf6 * (dkq6 - AT(6,0)*dl0 - AT(6,1)*dl1 - AT(6,2)*dl2 - AT(6,3)*dl3 - AT(6,4)*dl4 - AT(6,5)*dl5);
    float dl7  = bf7 * (dkq7 - AT(7,0)*dl0 - AT(7,1)*dl1 - AT(7,2)*dl2 - AT(7,3)*dl3 - AT(7,4)*dl4 - AT(7,5)*dl5 - AT(7,6)*dl6);
    float dl8  = bf8 * (dkq8 - AT(8,0)*dl0 - AT(8,1)*dl1 - AT(8,2)*dl2 - AT(8,3)*dl3 - AT(8,4)*dl4 - AT(8,5)*dl5 - AT(8,6)*dl6 - AT(8,7)*dl7);
    float dl9  = bf9 * (dkq9 - AT(9,0)*dl0 - AT(9,1)*dl1 - AT(9,2)*dl2 - AT(9,3)*dl3 - AT(9,4)*dl4 - AT(9,5)*dl5 - AT(9,6)*dl6 - AT(9,7)*dl7 - AT(9,8)*dl8);
    float dl10 = bf10 * (dkq10 - AT(10,0)*dl0 - AT(10,1)*dl1 - AT(10,2)*dl2 - AT(10,3)*dl3 - AT(10,4)*dl4 - AT(10,5)*dl5 - AT(10,6)*dl6 - AT(10,7)*dl7 - AT(10,8)*dl8 - AT(10,9)*dl9);
    float dl11 = bf11 * (dkq11 - AT(11,0)*dl0 - AT(11,1)*dl1 - AT(11,2)*dl2 - AT(11,3)*dl3 - AT(11,4)*dl4 - AT(11,5)*dl5 - AT(11,6)*dl6 - AT(11,7)*dl7 - AT(11,8)*dl8 - AT(11,9)*dl9 - AT(11,10)*dl10);
    float dl12 = bf12 * (dkq12 - AT(12,0)*dl0 - AT(12,1)*dl1 - AT(12,2)*dl2 - AT(12,3)*dl3 - AT(12,4)*dl4 - AT(12,5)*dl5 - AT(12,6)*dl6 - AT(12,7)*dl7 - AT(12,8)*dl8 - AT(12,9)*dl9 - AT(12,10)*dl10 - AT(12,11)*dl11);
    float dl13 = bf13 * (dkq13 - AT(13,0)*dl0 - AT(13,1)*dl1 - AT(13,2)*dl2 - AT(13,3)*dl3 - AT(13,4)*dl4 - AT(13,5)*dl5 - AT(13,6)*dl6 - AT(13,7)*dl7 - AT(13,8)*dl8 - AT(13,9)*dl9 - AT(13,10)*dl10 - AT(13,11)*dl11 - AT(13,12)*dl12);
    float dl14 = bf14 * (dkq14 - AT(14,0)*dl0 - AT(14,1)*dl1 - AT(14,2)*dl2 - AT(14,3)*dl3 - AT(14,4)*dl4 - AT(14,5)*dl5 - AT(14,6)*dl6 - AT(14,7)*dl7 - AT(14,8)*dl8 - AT(14,9)*dl9 - AT(14,10)*dl10 - AT(14,11)*dl11 - AT(14,12)*dl12 - AT(14,13)*dl13);
    float dl15 = bf15 * (dkq15 - AT(15,0)*dl0 - AT(15,1)*dl1 - AT(15,2)*dl2 - AT(15,3)*dl3 - AT(15,4)*dl4 - AT(15,5)*dl5 - AT(15,6)*dl6 - AT(15,7)*dl7 - AT(15,8)*dl8 - AT(15,9)*dl9 - AT(15,10)*dl10 - AT(15,11)*dl11 - AT(15,12)*dl12 - AT(15,13)*dl13 - AT(15,14)*dl14);

    // ---- phase 3: y_t = dqg_t + sum_{s<=t} Aq[t][s]*dl_s ----
    float Y = 0.f;
    {
      float yv;
      yv = dqg0 + AQ(0,0)*dl0;
      if (i == 0) Y = yv;
      yv = dqg1 + AQ(1,0)*dl0 + AQ(1,1)*dl1;
      if (i == 1) Y = yv;
      yv = dqg2 + AQ(2,0)*dl0 + AQ(2,1)*dl1 + AQ(2,2)*dl2;
      if (i == 2) Y = yv;
      yv = dqg3 + AQ(3,0)*dl0 + AQ(3,1)*dl1 + AQ(3,2)*dl2 + AQ(3,3)*dl3;
      if (i == 3) Y = yv;
      yv = dqg4 + AQ(4,0)*dl0 + AQ(4,1)*dl1 + AQ(4,2)*dl2 + AQ(4,3)*dl3 + AQ(4,4)*dl4;
      if (i == 4) Y = yv;
      yv = dqg5 + AQ(5,0)*dl0 + AQ(5,1)*dl1 + AQ(5,2)*dl2 + AQ(5,3)*dl3 + AQ(5,4)*dl4 + AQ(5,5)*dl5;
      if (i == 5) Y = yv;
      yv = dqg6 + AQ(6,0)*dl0 + AQ(6,1)*dl1 + AQ(6,2)*dl2 + AQ(6,3)*dl3 + AQ(6,4)*dl4 + AQ(6,5)*dl5 + AQ(6,6)*dl6;
      if (i == 6) Y = yv;
      yv = dqg7 + AQ(7,0)*dl0 + AQ(7,1)*dl1 + AQ(7,2)*dl2 + AQ(7,3)*dl3 + AQ(7,4)*dl4 + AQ(7,5)*dl5 + AQ(7,6)*dl6 + AQ(7,7)*dl7;
      if (i == 7) Y = yv;
      yv = dqg8 + AQ(8,0)*dl0 + AQ(8,1)*dl1 + AQ(8,2)*dl2 + AQ(8,3)*dl3 + AQ(8,4)*dl4 + AQ(8,5)*dl5 + AQ(8,6)*dl6 + AQ(8,7)*dl7 + AQ(8,8)*dl8;
      if (i == 8) Y = yv;
      yv = dqg9 + AQ(9,0)*dl0 + AQ(9,1)*dl1 + AQ(9,2)*dl2 + AQ(9,3)*dl3 + AQ(9,4)*dl4 + AQ(9,5)*dl5 + AQ(9,6)*dl6 + AQ(9,7)*dl7 + AQ(9,8)*dl8 + AQ(9,9)*dl9;
      if (i == 9) Y = yv;
      yv = dqg10 + AQ(10,0)*dl0 + AQ(10,1)*dl1 + AQ(10,2)*dl2 + AQ(10,3)*dl3 + AQ(10,4)*dl4 + AQ(10,5)*dl5 + AQ(10,6)*dl6 + AQ(10,7)*dl7 + AQ(10,8)*dl8 + AQ(10,9)*dl9 + AQ(10,10)*dl10;
      if (i == 10) Y = yv;
      yv = dqg11 + AQ(11,0)*dl0 + AQ(11,1)*dl1 + AQ(11,2)*dl2 + AQ(11,3)*dl3 + AQ(11,4)*dl4 + AQ(11,5)*dl5 + AQ(11,6)*dl6 + AQ(11,7)*dl7 + AQ(11,8)*dl8 + AQ(11,9)*dl9 + AQ(11,10)*dl10 + AQ(11,11)*dl11;
      if (i == 11) Y = yv;
      yv = dqg12 + AQ(12,0)*dl0 + AQ(12,1)*dl1 + AQ(12,2)*dl2 + AQ(12,3)*dl3 + AQ(12,4)*dl4 + AQ(12,5)*dl5 + AQ(12,6)*dl6 + AQ(12,7)*dl7 + AQ(12,8)*dl8 + AQ(12,9)*dl9 + AQ(12,10)*dl10 + AQ(12,11)*dl11 + AQ(12,12)*dl12;
      if (i == 12) Y = yv;
      yv = dqg13 + AQ(13,0)*dl0 + AQ(13,1)*dl1 + AQ(13,2)*dl2 + AQ(13,3)*dl3 + AQ(13,4)*dl4 + AQ(13,5)*dl5 + AQ(13,6)*dl6 + AQ(13,7)*dl7 + AQ(13,8)*dl8 + AQ(13,9)*dl9 + AQ(13,10)*dl10 + AQ(13,11)*dl11 + AQ(13,12)*dl12 + AQ(13,13)*dl13;
      if (i == 13) Y = yv;
      yv = dqg14 + AQ(14,0)*dl0 + AQ(14,1)*dl1 + AQ(14,2)*dl2 + AQ(14,3)*dl3 + AQ(14,4)*dl4 + AQ(14,5)*dl5 + AQ(14,6)*dl6 + AQ(14,7)*dl7 + AQ(14,8)*dl8 + AQ(14,9)*dl9 + AQ(14,10)*dl10 + AQ(14,11)*dl11 + AQ(14,12)*dl12 + AQ(14,13)*dl13 + AQ(14,14)*dl14;
      if (i == 14) Y = yv;
      yv = dqg15 + AQ(15,0)*dl0 + AQ(15,1)*dl1 + AQ(15,2)*dl2 + AQ(15,3)*dl3 + AQ(15,4)*dl4 + AQ(15,5)*dl5 + AQ(15,6)*dl6 + AQ(15,7)*dl7 + AQ(15,8)*dl8 + AQ(15,9)*dl9 + AQ(15,10)*dl10 + AQ(15,11)*dl11 + AQ(15,12)*dl12 + AQ(15,13)*dl13 + AQ(15,14)*dl14 + AQ(15,15)*dl15;
      if (i == 15) Y = yv;
    }
    ys[bhbase + (size_t)(T0 + i) * rowstride + e] = Y;

    // ---- phase 4: S = gam15*S0 + sum_s wgt[s]*dl_s*k_s (k reloaded, L1) ----
    {
      float g15 = tb[512 + 15];
      Sx *= g15; Sy *= g15; Sz *= g15; Sw *= g15;
#define P4(S)                                                              \
      {                                                                    \
        float4 ks4 = *(const float4*)(kp + (size_t)(T0 + S) * rowstride);  \
        float cs = tb[528 + S] * dl##S;                                    \
        Sx = fmaf(cs, ks4.x, Sx);                                          \
        Sy = fmaf(cs, ks4.y, Sy);                                          \
        Sz = fmaf(cs, ks4.z, Sz);                                          \
        Sw = fmaf(cs, ks4.w, Sw);                                          \
      }
      P4(0) P4(1) P4(2) P4(3) P4(4) P4(5) P4(6) P4(7)
      P4(8) P4(9) P4(10) P4(11) P4(12) P4(13) P4(14) P4(15)
#undef P4
    }
  }
#undef AT
#undef AQ
}

// ---------------------------------------------------------------------------
// ctx = rmsnorm(ys, norm_w) * silu(gate), written directly as hi/lo bf16
// (fuses the ctx cast_hilo pass: saves one 67 MB kernel).
// ---------------------------------------------------------------------------
__global__ __launch_bounds__(256)
void out_gate_kernel(const float* __restrict__ ys,
                     const float* __restrict__ g,
                     const float* __restrict__ norm_w,
                     unsigned short* __restrict__ chi,
                     unsigned short* __restrict__ clo)
{
  const int t = threadIdx.x, w = t >> 6, lane = t & 63;
  const int NP = M_ * H_;
  float nw = norm_w[lane];
  for (int p = blockIdx.x * 4 + w; p < NP; p += gridDim.x * 4) {
    size_t off = (size_t)p * 64 + lane;
    float y = ys[off];
    float gv = g[off];
    float s = y * y;
#pragma unroll
    for (int o = 32; o >= 1; o >>= 1) s += __shfl_xor(s, o, 64);
    float rs = rsqrtf(s * (1.0f / 64.0f) + 1e-6f);
    float silu = gv / (1.0f + expf(-gv));
    float c = y * rs * nw * silu;
    unsigned short hh = f2bf(c);
    chi[off] = hh;
    clo[off] = f2bf(c - bf2f(hh));
  }
}

// ---------------------------------------------------------------------------
extern "C" void kernel_launch(void* const* d_in, const int* in_sizes, int n_in,
                              void* d_out, int out_size, void* d_ws, size_t ws_size,
                              hipStream_t stream)
{
  const float* x   = (const float*)d_in[0];
  const float* Wq  = (const float*)d_in[1];
  const float* Wk  = (const float*)d_in[2];
  const float* Wv  = (const float*)d_in[3];
  const float* Wg  = (const float*)d_in[4];
  const float* Wb  = (const float*)d_in[5];
  const float* Wa  = (const float*)d_in[6];
  const float* dtb = (const float*)d_in[7];
  const float* Alg = (const float*)d_in[8];
  const float* nw  = (const float*)d_in[9];
  const float* Wo  = (const float*)d_in[10];
  const float* bo  = (const float*)d_in[11];

  const size_t TSZ = (size_t)M_ * DOUT;   // 8,388,608
  const size_t WSZ = (size_t)DOUT * DIN;  // 1,048,576

  float* q    = (float*)d_ws;             // projections q,k,v,g,bta contiguous
  float* k    = q + TSZ;
  float* v    = k + TSZ;
  float* g    = v + TSZ;
  float* bta  = g + TSZ;
  float* ys   = bta + TSZ;
  float* alph = ys + TSZ;                 // M_*H_ floats
  unsigned short* whl = (unsigned short*)(alph + (size_t)M_ * H_);
  unsigned short* whi[6], *wlo[6];
  for (int j = 0; j < 6; j++) { whi[j] = whl + (size_t)(2 * j) * WSZ; wlo[j] = whl + (size_t)(2 * j + 1) * WSZ; }
  // x hi/lo aliased into ys region (dead until scan)
  unsigned short* xhi = (unsigned short*)ys;
  unsigned short* xlo = xhi + TSZ;
  // ctx hi/lo aliased into q region (q dead after scan)
  unsigned short* chi = (unsigned short*)q;
  unsigned short* clo = chi + TSZ;
  float* outp = (float*)d_out;
  // chunk tables aliased into d_out (17.8 MB < 33.5 MB; d_out written only by
  // final_gemm, which runs after the scan consumed the tables — R1-validated).
  float* tabw = (float*)d_out;

  cast_hilo<<<2048, 256, 0, stream>>>(x, xhi, xlo, (int)TSZ);
  cast_hilo<<<512, 256, 0, stream>>>(Wq, whi[0], wlo[0], (int)WSZ);
  cast_hilo<<<512, 256, 0, stream>>>(Wk, whi[1], wlo[1], (int)WSZ);
  cast_hilo<<<512, 256, 0, stream>>>(Wv, whi[2], wlo[2], (int)WSZ);
  cast_hilo<<<512, 256, 0, stream>>>(Wg, whi[3], wlo[3], (int)WSZ);
  cast_hilo<<<512, 256, 0, stream>>>(Wb, whi[4], wlo[4], (int)WSZ);
  cast_hilo<<<512, 256, 0, stream>>>(Wo, whi[5], wlo[5], (int)WSZ);

  WPtrs wp;
  for (int j = 0; j < 5; j++) { wp.hi[j] = whi[j]; wp.lo[j] = wlo[j]; }
  dim3 gp(M_ / 128, DOUT / 128, 5);
  proj_gemm<<<gp, 256, 0, stream>>>(xhi, xlo, wp, q);

  alpha_kernel<<<128, 256, 0, stream>>>(x, Wa, dtb, Alg, alph);
  qkb_kernel<<<1024, 256, 0, stream>>>(q, k, bta);
  chunk_tab_kernel<<<64 * NC_, 256, 0, stream>>>(q, k, alph, tabw);
  scan_kernel<<<256, 256, 0, stream>>>(q, k, v, bta, tabw, ys);
  out_gate_kernel<<<1024, 256, 0, stream>>>(ys, g, nw, chi, clo);

  dim3 gf(M_ / 128, DOUT / 128);
  final_gemm<<<gf, 256, 0, stream>>>(chi, clo, whi[5], wlo[5], outp, bo);
}